// Round 3
// baseline (710.864 us; speedup 1.0000x reference)
//
#include <hip/hip_runtime.h>
#include <hip/hip_bf16.h>
#include <stdint.h>

#define S_ 2048
#define D_ 1024
#define B_ 8
#define KEXP 3072            // 3 * D : [h,l,h] x [h,h,l] fp16 expansion
#define NEGC 1e9f

typedef _Float16 f16;
typedef _Float16 f16x8 __attribute__((ext_vector_type(8)));
typedef float f32x4 __attribute__((ext_vector_type(4)));

// LDS swizzle: involution on byte offsets within a [row][64B] tile.
// Flips chunk bits 4-5 by row bits 1-2 ((L>>7)&3): spreads 16-lane same-col
// fragment reads across 8 distinct bank positions (~2-way = free, m136).
__device__ __forceinline__ int swz(int x) { return x ^ (((x >> 7) & 3) << 4); }

// ---------------------------------------------------------------------------
// K0a/K0b: split fp32 -> fp16 hi/lo 3-term expansion, input pre-scaled by 64.
// pattern A (q): out[3t]=h, out[3t+1]=l, out[3t+2]=h
// pattern B (k): out[3t]=h, out[3t+1]=h, out[3t+2]=l
// ---------------------------------------------------------------------------
__global__ __launch_bounds__(256) void split_expand(const float* __restrict__ in,
                                                    f16* __restrict__ out, int isB) {
  size_t idx = (size_t)blockIdx.x * 256 + threadIdx.x;   // one thread per 8 floats
  const float4* ip = (const float4*)(in + idx * 8);
  float4 a = ip[0], b = ip[1];
  float vv[8] = {a.x, a.y, a.z, a.w, b.x, b.y, b.z, b.w};
  union { f16 h[24]; uint4 u[3]; } o;
#pragma unroll
  for (int t = 0; t < 8; ++t) {
    float v = vv[t] * 64.0f;
    f16 h = (f16)v;
    float r = v - (float)h;      // exact (Sterbenz)
    f16 l = (f16)r;
    o.h[3 * t + 0] = h;
    o.h[3 * t + 1] = isB ? h : l;
    o.h[3 * t + 2] = isB ? l : h;
  }
  uint4* op = (uint4*)(out + idx * 24);
  op[0] = o.u[0]; op[1] = o.u[1]; op[2] = o.u[2];
}

// ---------------------------------------------------------------------------
// K0c: khT[b][d][j] = fp16(k[b][j][d])  (plain cast, no prescale) for PV GEMM
// ---------------------------------------------------------------------------
__global__ __launch_bounds__(256) void transpose_cast(const float* __restrict__ k,
                                                      f16* __restrict__ khT) {
  __shared__ f16 tile[64][65];
  int j0 = blockIdx.x * 64, d0 = blockIdx.y * 64;
  size_t bz = blockIdx.z;
  const float* kb = k + bz * (size_t)S_ * D_;
  f16* ob = khT + bz * (size_t)D_ * S_;
#pragma unroll
  for (int i = 0; i < 16; ++i) {
    int e = threadIdx.x + i * 256;
    int r = e >> 6, c = e & 63;              // r: j-local, c: d-local
    tile[c][r] = (f16)kb[(size_t)(j0 + r) * D_ + d0 + c];
  }
  __syncthreads();
#pragma unroll
  for (int i = 0; i < 16; ++i) {
    int e = threadIdx.x + i * 256;
    int r = e >> 6, c = e & 63;              // r: d-local, c: j-local
    ob[(size_t)(d0 + r) * S_ + j0 + c] = tile[r][c];
  }
}

// ---------------------------------------------------------------------------
// GEMM (B-transposed): C[m,n] = (sum_k A[m,k]*B[n,k]) * mult
// 256x256 tile, BK=32, 8 waves (2M x 4N), ring-3 LDS, prefetch depth 2,
// counted vmcnt(4) (never drains in main loop), st-swizzled LDS, setprio
// around MFMA clusters. K-accumulation order identical to the plain loop
// (one 16x16x32 MFMA per k-tile per fragment) -> bit-identical results.
// ---------------------------------------------------------------------------
template <int KA, int NN>
__global__ __launch_bounds__(512, 2) void gemm256(const f16* __restrict__ A,
                                                  const f16* __restrict__ Bm,
                                                  float* __restrict__ C,
                                                  const float* scale_ptr, float factor) {
  __shared__ f16 As[3][256 * 32];   // 3 slots x 16KB
  __shared__ f16 Bs[3][256 * 32];
  const int tid = threadIdx.x;
  const int lane = tid & 63, wave = tid >> 6;
  const int wm = wave >> 2, wn = wave & 3;          // 2 x 4 wave grid
  const size_t bz = blockIdx.z;
  const f16* Ab = A + bz * (size_t)S_ * KA + (size_t)blockIdx.x * 256 * KA;
  const f16* Bb = Bm + bz * (size_t)NN * KA + (size_t)blockIdx.y * 256 * KA;

  // staging source map: thread covers physical LDS bytes p = i*8192+wave*1024+lane*16
  // (linear dest for global_load_lds); fetch from the inverse-swizzled logical spot.
  int prow[2], pcol[2];
#pragma unroll
  for (int i = 0; i < 2; ++i) {
    int p = i * 8192 + wave * 1024 + lane * 16;
    int l = swz(p);
    prow[i] = l >> 6;                 // logical row 0..255
    pcol[i] = (l & 63) >> 1;          // f16 element within row
  }

  f32x4 acc[8][4];
#pragma unroll
  for (int i = 0; i < 8; ++i)
#pragma unroll
    for (int j = 0; j < 4; ++j)
#pragma unroll
      for (int r = 0; r < 4; ++r) acc[i][j][r] = 0.0f;

  auto stageA = [&](int slot, int kt) {
#pragma unroll
    for (int i = 0; i < 2; ++i) {
      const f16* src = Ab + (size_t)prow[i] * KA + kt * 32 + pcol[i];
      f16* dst = &As[slot][i * 4096 + wave * 512];   // wave-uniform base
      __builtin_amdgcn_global_load_lds((const __attribute__((address_space(1))) void*)src,
                                       (__attribute__((address_space(3))) void*)dst, 16, 0, 0);
    }
  };
  auto stageB = [&](int slot, int kt) {
#pragma unroll
    for (int i = 0; i < 2; ++i) {
      const f16* src = Bb + (size_t)prow[i] * KA + kt * 32 + pcol[i];
      f16* dst = &Bs[slot][i * 4096 + wave * 512];
      __builtin_amdgcn_global_load_lds((const __attribute__((address_space(1))) void*)src,
                                       (__attribute__((address_space(3))) void*)dst, 16, 0, 0);
    }
  };

  const int cb = (lane >> 4) * 16;    // fragment k-chunk byte offset
  const int fr = lane & 15;           // fragment row within 16

  // one K-tile (BK=32): 2 phases x {ds_read || stage || barrier || 16 MFMA}
  auto do_tile = [&](int t, int sk, int vm) {
    const int slot = t % 3;
    const int nslot = (t + 2) % 3;
    const char* as = (const char*)&As[slot][0];
    const char* bs = (const char*)&Bs[slot][0];
    f16x8 af[4], bf[4];
    // ---- phase A: A m0-3, B n0-3 reads; stage A(t+2); MFMA m0-3 x n0-3
#pragma unroll
    for (int m = 0; m < 4; ++m) {
      int L = (wm * 128 + m * 16 + fr) * 64 + cb;
      af[m] = *(const f16x8*)(as + swz(L));
    }
#pragma unroll
    for (int n = 0; n < 4; ++n) {
      int L = (wn * 64 + n * 16 + fr) * 64 + cb;
      bf[n] = *(const f16x8*)(bs + swz(L));
    }
    if (sk >= 0) stageA(nslot, sk);
    __builtin_amdgcn_s_barrier();
    __builtin_amdgcn_s_setprio(1);
#pragma unroll
    for (int m = 0; m < 4; ++m)
#pragma unroll
      for (int n = 0; n < 4; ++n)
        acc[m][n] = __builtin_amdgcn_mfma_f32_16x16x32_f16(af[m], bf[n], acc[m][n], 0, 0, 0);
    __builtin_amdgcn_s_setprio(0);
    __builtin_amdgcn_s_barrier();
    // ---- phase B: A m4-7 reads; stage B(t+2); MFMA m4-7 x n0-3
#pragma unroll
    for (int m = 0; m < 4; ++m) {
      int L = (wm * 128 + (m + 4) * 16 + fr) * 64 + cb;
      af[m] = *(const f16x8*)(as + swz(L));
    }
    if (sk >= 0) stageB(nslot, sk);
    __builtin_amdgcn_s_barrier();
    __builtin_amdgcn_s_setprio(1);
#pragma unroll
    for (int m = 0; m < 4; ++m)
#pragma unroll
      for (int n = 0; n < 4; ++n)
        acc[m + 4][n] = __builtin_amdgcn_mfma_f32_16x16x32_f16(af[m], bf[n], acc[m + 4][n], 0, 0, 0);
    __builtin_amdgcn_s_setprio(0);
    if (vm == 4) asm volatile("s_waitcnt vmcnt(4)" ::: "memory");
    else if (vm == 0) asm volatile("s_waitcnt vmcnt(0)" ::: "memory");
    __builtin_amdgcn_s_barrier();
  };

  constexpr int NT = KA / 32;
  // prologue: tiles 0 and 1 in flight; wait for tile 0 only
  stageA(0, 0); stageB(0, 0);
  stageA(1, 1); stageB(1, 1);
  asm volatile("s_waitcnt vmcnt(4)" ::: "memory");
  __builtin_amdgcn_s_barrier();

#pragma unroll 1
  for (int t = 0; t <= NT - 3; ++t) do_tile(t, t + 2, 4);
  do_tile(NT - 2, -1, 0);
  do_tile(NT - 1, -1, -1);

  float scl = factor;
  if (scale_ptr != nullptr) scl = factor * scale_ptr[0];
  float* Cb = C + bz * (size_t)S_ * NN;
  const int rowb = blockIdx.x * 256 + wm * 128 + ((lane >> 4) << 2);
  const int colb = blockIdx.y * 256 + wn * 64 + fr;
#pragma unroll
  for (int i = 0; i < 8; ++i)
#pragma unroll
    for (int j = 0; j < 4; ++j)
#pragma unroll
      for (int r = 0; r < 4; ++r)
        Cb[(size_t)(rowb + i * 16 + r) * NN + colb + j * 16] = acc[i][j][r] * scl;
}

// ---------------------------------------------------------------------------
// reductions
// ---------------------------------------------------------------------------
__device__ __forceinline__ float block_reduce_max(float v, float* red, int tid) {
#pragma unroll
  for (int o = 32; o > 0; o >>= 1) v = fmaxf(v, __shfl_xor(v, o, 64));
  __syncthreads();
  if ((tid & 63) == 0) red[tid >> 6] = v;
  __syncthreads();
  return fmaxf(fmaxf(red[0], red[1]), fmaxf(red[2], red[3]));
}
__device__ __forceinline__ float block_reduce_sum(float v, float* red, int tid) {
#pragma unroll
  for (int o = 32; o > 0; o >>= 1) v += __shfl_xor(v, o, 64);
  __syncthreads();
  if ((tid & 63) == 0) red[4 + (tid >> 6)] = v;
  __syncthreads();
  return (red[4] + red[5]) + (red[6] + red[7]);
}

// ---------------------------------------------------------------------------
// K2: row softmax for VALID query rows; padding rows -> P row = 0.
// ---------------------------------------------------------------------------
__global__ __launch_bounds__(256) void softmax_rows(const float* __restrict__ scores,
                                                    const int* __restrict__ mask,
                                                    f16* __restrict__ P, int b0) {
  __shared__ float red[8];
  const int q = blockIdx.x, bl = blockIdx.y, bg = b0 + bl;
  const int tid = threadIdx.x;
  const float* srow = scores + ((size_t)bl * S_ + q) * S_;
  f16* prow = P + ((size_t)bl * S_ + q) * S_;
  if (mask[bg * S_ + q] == 0) {
    uint4 z = {0, 0, 0, 0};
    ((uint4*)prow)[tid] = z;   // 256 threads x 16B = 4096B row
    return;
  }
  const int j0 = tid * 8;
  float4 s0v = *(const float4*)(srow + j0);
  float4 s1v = *(const float4*)(srow + j0 + 4);
  int4 m0 = *(const int4*)(mask + (size_t)bg * S_ + j0);
  int4 m1 = *(const int4*)(mask + (size_t)bg * S_ + j0 + 4);
  float sv[8] = {s0v.x, s0v.y, s0v.z, s0v.w, s1v.x, s1v.y, s1v.z, s1v.w};
  int mk[8] = {m0.x, m0.y, m0.z, m0.w, m1.x, m1.y, m1.z, m1.w};
  int fl[8];
  float lm = -3.4e38f;
#pragma unroll
  for (int i = 0; i < 8; ++i) {
    fl[i] = (j0 + i <= q) && (mk[i] != 0);
    if (fl[i]) lm = fmaxf(lm, sv[i]);
  }
  float m = block_reduce_max(lm, red, tid);
  float ls = 0.0f;
#pragma unroll
  for (int i = 0; i < 8; ++i) {
    float e = fl[i] ? expf(sv[i] - m) : 0.0f;
    sv[i] = e; ls += e;
  }
  float sum = block_reduce_sum(ls, red, tid);
  float inv = 1.0f / sum;
  union { f16 h[8]; uint4 u; } ow;
#pragma unroll
  for (int i = 0; i < 8; ++i) ow.h[i] = (f16)(sv[i] * inv);
  *(uint4*)(prow + j0) = ow.u;
}

// ---------------------------------------------------------------------------
// K4: padding query rows — replicate fp32 quantization of fl(s-1e9):
// softmax = uniform mean over the top 64-wide bucket; boundary entries get
// an exact (double) recompute. Ordered match list via block prefix scan.
// ---------------------------------------------------------------------------
__global__ __launch_bounds__(256) void padrows(const float* __restrict__ scores,
                                               const int* __restrict__ mask,
                                               const float* __restrict__ qg,
                                               const float* __restrict__ kg,
                                               const float* __restrict__ scale_ptr,
                                               float* __restrict__ out, int b0) {
  const int q = blockIdx.x, bl = blockIdx.y, bg = b0 + bl;
  if (mask[bg * S_ + q] != 0) return;
  const int tid = threadIdx.x;
  __shared__ int idxs[S_];
  __shared__ int scn[256];
  __shared__ float red[8];
  const float* srow = scores + ((size_t)bl * S_ + q) * S_;
  const float scl = scale_ptr[0];
  const int j0 = tid * 8;

  float4 s0v = *(const float4*)(srow + j0);
  float4 s1v = *(const float4*)(srow + j0 + 4);
  float sv[8] = {s0v.x, s0v.y, s0v.z, s0v.w, s1v.x, s1v.y, s1v.z, s1v.w};
  float vv[8];
  float lm = -3.4e38f;
#pragma unroll
  for (int i = 0; i < 8; ++i) {
    vv[i] = sv[i] - NEGC;             // fl(s - 1e9): quantized to 64-grid
    lm = fmaxf(lm, vv[i]);
  }
  float g0 = block_reduce_max(lm, red, tid);

  float lm2 = -3.4e38f;
#pragma unroll 1
  for (int i = 0; i < 8; ++i) {
    float s = sv[i];
    float t = s * (1.0f / 64.0f);     // exact scaling by power of 2
    float rn = rintf(t);
    float dist = (0.5f - fabsf(t - rn)) * 64.0f;   // distance to rounding boundary
    float v = vv[i];
    if (dist < 1e-3f && v >= g0 - 64.5f) {
      const float* qr = qg + ((size_t)bg * S_ + q) * D_;
      const float* kr = kg + ((size_t)bg * S_ + j0 + i) * D_;
      double acc = 0.0;
      for (int t2 = 0; t2 < D_; ++t2) acc += (double)qr[t2] * (double)kr[t2];
      float sx = (float)acc * scl;
      v = sx - NEGC;
    }
    vv[i] = v;
    lm2 = fmaxf(lm2, v);
  }
  float gf = block_reduce_max(lm2, red, tid);

  // ordered (j-sorted) match collection via block prefix scan
  int local = 0, flags = 0;
#pragma unroll
  for (int i = 0; i < 8; ++i) {
    int mt = (vv[i] == gf) ? 1 : 0;
    flags |= mt << i;
    local += mt;
  }
  scn[tid] = local;
  __syncthreads();
#pragma unroll
  for (int o = 1; o < 256; o <<= 1) {
    int v2 = (tid >= o) ? scn[tid - o] : 0;
    __syncthreads();
    scn[tid] += v2;
    __syncthreads();
  }
  int total = scn[255];
  int base = scn[tid] - local;
  int w = 0;
#pragma unroll
  for (int i = 0; i < 8; ++i)
    if ((flags >> i) & 1) idxs[base + (w++)] = j0 + i;
  __syncthreads();

  // cooperative mean over matched k rows (thread owns 4 d-columns)
  const float* kb = kg + (size_t)bg * S_ * D_;
  float a0 = 0, a1 = 0, a2 = 0, a3 = 0;
#pragma unroll 4
  for (int m2 = 0; m2 < total; ++m2) {
    const float4 kv = *(const float4*)(kb + (size_t)idxs[m2] * D_ + tid * 4);
    a0 += kv.x; a1 += kv.y; a2 += kv.z; a3 += kv.w;
  }
  float invc = 1.0f / (float)total;
  float4 o = {a0 * invc, a1 * invc, a2 * invc, a3 * invc};
  *(float4*)(out + ((size_t)bg * S_ + q) * D_ + tid * 4) = o;
}

// ---------------------------------------------------------------------------
extern "C" void kernel_launch(void* const* d_in, const int* in_sizes, int n_in,
                              void* d_out, int out_size, void* d_ws, size_t ws_size,
                              hipStream_t stream) {
  (void)in_sizes; (void)n_in; (void)out_size;
  const float* q = (const float*)d_in[0];
  const float* k = (const float*)d_in[1];
  const int* mask = (const int*)d_in[2];
  const float* scale = (const float*)d_in[3];
  float* out = (float*)d_out;

  const size_t per_qx = (size_t)S_ * KEXP * 2;     // 12.58 MB
  const size_t per_khT = (size_t)D_ * S_ * 2;      //  4.19 MB
  const size_t per_sc = (size_t)S_ * S_ * 4;       // 16.78 MB
  const size_t per_P = (size_t)S_ * S_ * 2;        //  8.39 MB
  const size_t per_batch = 2 * per_qx + per_khT + per_sc + per_P;

  int nb = (int)(ws_size / per_batch);
  if (nb > B_) nb = B_;
  if (nb < 1) nb = 1;

  char* w = (char*)d_ws;
  f16* qx = (f16*)w;
  f16* kx = (f16*)(w + (size_t)nb * per_qx);
  f16* khT = (f16*)(w + (size_t)nb * per_qx * 2);
  float* sc = (float*)(w + (size_t)nb * (per_qx * 2 + per_khT));
  f16* P = (f16*)(w + (size_t)nb * (per_qx * 2 + per_khT + per_sc));

  for (int b0 = 0; b0 < B_; b0 += nb) {
    int cb = (B_ - b0 < nb) ? (B_ - b0) : nb;
    const float* qb = q + (size_t)b0 * S_ * D_;
    const float* kb = k + (size_t)b0 * S_ * D_;

    int blocks0 = cb * ((S_ * D_ / 8) / 256);  // cb * 1024
    split_expand<<<dim3(blocks0), dim3(256), 0, stream>>>(qb, qx, 0);
    split_expand<<<dim3(blocks0), dim3(256), 0, stream>>>(kb, kx, 1);
    transpose_cast<<<dim3(S_ / 64, D_ / 64, cb), dim3(256), 0, stream>>>(kb, khT);

    // scores = (q.k) * scale : factor 2^-12 undoes the 64x prescale on q,k
    gemm256<KEXP, S_><<<dim3(8, 8, cb), dim3(512), 0, stream>>>(
        qx, kx, sc, scale, 0.000244140625f);

    softmax_rows<<<dim3(S_, cb), dim3(256), 0, stream>>>(sc, mask, P, b0);

    gemm256<S_, D_><<<dim3(8, 4, cb), dim3(512), 0, stream>>>(
        P, khT, out + (size_t)b0 * S_ * D_, nullptr, 1.0f);

    padrows<<<dim3(S_, cb), dim3(256), 0, stream>>>(sc, mask, q, k, scale, out, b0);
  }
}